// Round 5
// baseline (17165.083 us; speedup 1.0000x reference)
//
#include <hip/hip_runtime.h>
#include <hip/hip_bf16.h>
#include <hip/hip_cooperative_groups.h>

namespace cg = cooperative_groups;

typedef short bf16x8 __attribute__((ext_vector_type(8)));
typedef float f32x4  __attribute__((ext_vector_type(4)));

#define SLEN 1024
#define NB   128
#define DIN  256
#define HID  512
#define NCLS 10
#define KTOT 768      // 512 (h) + 256 (x)
#define NBLK 64
#define CH   8        // h-columns per block
#define TN   32       // 4 gates * CH output cols per block
#define LDSK 776      // 768 + 8 bf16 pad (16B) to break bank-stride

__device__ __forceinline__ unsigned short f2bf(float x) {
    union { float f; unsigned u; } v; v.f = x;
    unsigned r = v.u + 0x7fffu + ((v.u >> 16) & 1u);
    return (unsigned short)(r >> 16);
}
__device__ __forceinline__ float bf2f(unsigned short b) {
    union { unsigned u; float f; } v; v.u = ((unsigned)b) << 16;
    return v.f;
}
__device__ __forceinline__ float sigf(float x) {
    return 1.0f / (1.0f + __expf(-x));
}
__device__ __forceinline__ float tanh_fast(float x) {
    float t = __expf(-2.0f * fabsf(x));
    float r = (1.0f - t) / (1.0f + t);
    return copysignf(r, x);
}

// ---------------- Kernel 1: x [B,S,D] fp32 -> xb [S,B,D] bf16 ----------------
__global__ void __launch_bounds__(256) k_convert_x(const float* __restrict__ x,
                                                   unsigned short* __restrict__ xb) {
    int idx = blockIdx.x * 256 + threadIdx.x;      // over B*S*(D/8)
    int d8  = idx & 31;                            // D/8 = 32
    int bs  = idx >> 5;                            // b*SLEN + s
    int s   = bs & (SLEN - 1);
    int b   = bs >> 10;
    const float* src = x + ((size_t)bs * DIN) + d8 * 8;
    float4 v0 = *(const float4*)(src);
    float4 v1 = *(const float4*)(src + 4);
    unsigned short o[8] = {f2bf(v0.x), f2bf(v0.y), f2bf(v0.z), f2bf(v0.w),
                           f2bf(v1.x), f2bf(v1.y), f2bf(v1.z), f2bf(v1.w)};
    bf16x8 pack;
    #pragma unroll
    for (int i = 0; i < 8; ++i) pack[i] = (short)o[i];
    *(bf16x8*)(xb + ((size_t)(s * NB + b) * DIN) + d8 * 8) = pack;
}

// ------- Kernel 2: build WT [2048][768] bf16 (WT[g*512+hc][k]) + zero h -------
__global__ void __launch_bounds__(256) k_build_wt(
    const float* __restrict__ Wgx, const float* __restrict__ Wix,
    const float* __restrict__ Wfx, const float* __restrict__ Wox,
    const float* __restrict__ Wgh, const float* __restrict__ Wih,
    const float* __restrict__ Wfh, const float* __restrict__ Woh,
    unsigned short* __restrict__ WT, unsigned short* __restrict__ h01) {
    int idx = blockIdx.x * 256 + threadIdx.x;      // 2048*768
    int col = idx / KTOT;
    int k   = idx - col * KTOT;
    int g   = col >> 9;
    int hc  = col & 511;
    const float* Wh[4] = {Wgh, Wih, Wfh, Woh};
    const float* Wx[4] = {Wgx, Wix, Wfx, Wox};
    float v = (k < HID) ? Wh[g][k * HID + hc] : Wx[g][(k - HID) * HID + hc];
    WT[idx] = f2bf(v);
    if (idx < 2 * NB * HID) h01[idx] = 0;          // zero both h buffers
}

// ---------------- Kernel 3: persistent cooperative LSTM scan ----------------
__global__ void __launch_bounds__(256) k_scan(
    const unsigned short* __restrict__ xb, const unsigned short* __restrict__ WT,
    unsigned short* __restrict__ h0, unsigned short* __restrict__ h1,
    const float* __restrict__ bg, const float* __restrict__ bi,
    const float* __restrict__ bfp, const float* __restrict__ bo,
    const float* __restrict__ Wph, const float* __restrict__ bp,
    float* __restrict__ out) {
    __shared__ unsigned short wt_lds[TN][LDSK];

    const int j   = blockIdx.x;          // 0..63, owns h-cols [j*8, j*8+8)
    const int tid = threadIdx.x;
    const int w   = tid >> 6;            // wave 0..3 -> rows [32w, 32w+32)
    const int l   = tid & 63;
    const int colbase = j * CH;

    // stage this block's 32x768 weight slice into LDS (once)
    for (int it = tid; it < TN * (KTOT / 8); it += 256) {
        int r  = it / (KTOT / 8);
        int c8 = it - r * (KTOT / 8);
        int g  = r >> 3, hc = r & 7;
        bf16x8 v = *(const bf16x8*)(WT + (size_t)(g * HID + colbase + hc) * KTOT + c8 * 8);
        *(bf16x8*)&wt_lds[r][c8 * 8] = v;
    }
    __syncthreads();

    const int  tc0  = l & 15;            // tile col of nfrag0 (nfrag1 = +16)
    const int  g4   = l >> 4;            // row group within fragment
    const bool lead = (tc0 < 8);
    const float* barr[4] = {bg, bi, bfp, bo};
    const float bias0 = barr[tc0 >> 3][colbase + (tc0 & 7)];
    const float bias1 = barr[2 + (tc0 >> 3)][colbase + (tc0 & 7)];

    float c_st[2][4];
    #pragma unroll
    for (int m = 0; m < 2; ++m)
        #pragma unroll
        for (int r = 0; r < 4; ++r) c_st[m][r] = 0.0f;

    unsigned short* hb[2] = {h0, h1};
    cg::grid_group grid = cg::this_grid();

    for (int s = 0; s < SLEN; ++s) {
        const unsigned short* hprev = hb[s & 1];
        unsigned short*       hnext = hb[(s + 1) & 1];
        const unsigned short* xs    = xb + (size_t)s * (NB * DIN);

        f32x4 acc[2][2];
        #pragma unroll
        for (int m = 0; m < 2; ++m)
            #pragma unroll
            for (int n = 0; n < 2; ++n) acc[m][n] = (f32x4){0.f, 0.f, 0.f, 0.f};

        #pragma unroll
        for (int kf = 0; kf < KTOT / 32; ++kf) {       // 24 k-steps of 32
            bf16x8 a0, a1;
            if (kf < 16) {
                const unsigned short* base = hprev + (size_t)(32 * w + tc0) * HID + kf * 32 + g4 * 8;
                a0 = *(const bf16x8*)(base);
                a1 = *(const bf16x8*)(base + 16 * HID);
            } else {
                const unsigned short* base = xs + (size_t)(32 * w + tc0) * DIN + (kf - 16) * 32 + g4 * 8;
                a0 = *(const bf16x8*)(base);
                a1 = *(const bf16x8*)(base + 16 * DIN);
            }
            bf16x8 b0 = *(const bf16x8*)&wt_lds[tc0][kf * 32 + g4 * 8];
            bf16x8 b1 = *(const bf16x8*)&wt_lds[16 + tc0][kf * 32 + g4 * 8];
            acc[0][0] = __builtin_amdgcn_mfma_f32_16x16x32_bf16(a0, b0, acc[0][0], 0, 0, 0);
            acc[0][1] = __builtin_amdgcn_mfma_f32_16x16x32_bf16(a0, b1, acc[0][1], 0, 0, 0);
            acc[1][0] = __builtin_amdgcn_mfma_f32_16x16x32_bf16(a1, b0, acc[1][0], 0, 0, 0);
            acc[1][1] = __builtin_amdgcn_mfma_f32_16x16x32_bf16(a1, b1, acc[1][1], 0, 0, 0);
        }

        // elementwise gate update: lane pair (l, l^8) holds (g,f) / (i,o) for same hc
        #pragma unroll
        for (int m = 0; m < 2; ++m) {
            #pragma unroll
            for (int r = 0; r < 4; ++r) {
                float p0 = acc[m][0][r] + bias0;
                float p1 = acc[m][1][r] + bias1;
                float a0 = lead ? tanh_fast(p0) : sigf(p0);   // g : i
                float a1 = sigf(p1);                          // f : o
                float e0 = __shfl_xor(a0, 8);
                float e1 = __shfl_xor(a1, 8);
                if (lead) {
                    float gg = a0, ff = a1, ii = e0, oo = e1;
                    float c  = gg * ii + c_st[m][r] * ff;
                    c_st[m][r] = c;
                    float h  = tanh_fast(c) * oo;
                    int row  = 32 * w + 16 * m + 4 * g4 + r;
                    hnext[row * HID + colbase + tc0] = f2bf(h);
                }
            }
        }
        grid.sync();
    }

    // classifier head: final h is in h0 (SLEN even)
    int gtid = blockIdx.x * 256 + tid;
    if (gtid < NB * NCLS) {
        int row = gtid / NCLS, cls = gtid - row * NCLS;
        const unsigned short* hrow = h0 + row * HID;
        float accf = bp[cls];
        for (int k = 0; k < HID; ++k)
            accf += bf2f(hrow[k]) * Wph[k * NCLS + cls];
        out[gtid] = accf;
    }
}

// ---------------------------------- launch ----------------------------------
extern "C" void kernel_launch(void* const* d_in, const int* in_sizes, int n_in,
                              void* d_out, int out_size, void* d_ws, size_t ws_size,
                              hipStream_t stream) {
    const float* x   = (const float*)d_in[0];
    const float* Wgx = (const float*)d_in[1];
    const float* Wix = (const float*)d_in[2];
    const float* Wfx = (const float*)d_in[3];
    const float* Wox = (const float*)d_in[4];
    const float* Wgh = (const float*)d_in[5];
    const float* Wih = (const float*)d_in[6];
    const float* Wfh = (const float*)d_in[7];
    const float* Woh = (const float*)d_in[8];
    const float* bg  = (const float*)d_in[9];
    const float* bi  = (const float*)d_in[10];
    const float* bfp = (const float*)d_in[11];
    const float* bo  = (const float*)d_in[12];
    const float* Wph = (const float*)d_in[13];
    const float* bp  = (const float*)d_in[14];
    float* out = (float*)d_out;

    unsigned short* xb = (unsigned short*)d_ws;                  // 1024*128*256
    unsigned short* WT = xb + (size_t)SLEN * NB * DIN;           // 2048*768
    unsigned short* h0 = WT + (size_t)4 * HID * KTOT;            // 128*512
    unsigned short* h1 = h0 + NB * HID;

    hipLaunchKernelGGL(k_convert_x, dim3(NB * SLEN * (DIN / 8) / 256), dim3(256), 0, stream, x, xb);
    hipLaunchKernelGGL(k_build_wt, dim3(4 * HID * KTOT / 256), dim3(256), 0, stream,
                       Wgx, Wix, Wfx, Wox, Wgh, Wih, Wfh, Woh, WT, h0);

    const unsigned short* xb_a = xb;
    const unsigned short* WT_a = WT;
    unsigned short* h0_a = h0;
    unsigned short* h1_a = h1;
    const float *bg_a = bg, *bi_a = bi, *bf_a = bfp, *bo_a = bo, *Wph_a = Wph, *bp_a = bp;
    float* out_a = out;
    void* args[] = {(void*)&xb_a, (void*)&WT_a, (void*)&h0_a, (void*)&h1_a,
                    (void*)&bg_a, (void*)&bi_a, (void*)&bf_a, (void*)&bo_a,
                    (void*)&Wph_a, (void*)&bp_a, (void*)&out_a};
    hipLaunchCooperativeKernel((const void*)k_scan, dim3(NBLK), dim3(256), args, 0, stream);
}

// Round 8
// 11836.089 us; speedup vs baseline: 1.4502x; 1.4502x over previous
//
#include <hip/hip_runtime.h>
#include <hip/hip_bf16.h>

typedef short bf16x8 __attribute__((ext_vector_type(8)));
typedef float f32x4  __attribute__((ext_vector_type(4)));

#define SLEN 1024
#define NB   128
#define DIN  256
#define HID  512
#define NCLS 10
#define KTOT 768      // 512 (h) + 256 (x)
#define NBLK 64
#define CH   8        // h-columns per block
#define TN   32       // 4 gates * CH output cols per block
#define LDSK 776      // 768 + 8 bf16 pad (16B) to break bank-stride
#define FSTRIDE 32    // flag stride in u32 (128B cacheline separation)

__device__ __forceinline__ unsigned short f2bf(float x) {
    union { float f; unsigned u; } v; v.f = x;
    unsigned r = v.u + 0x7fffu + ((v.u >> 16) & 1u);
    return (unsigned short)(r >> 16);
}
__device__ __forceinline__ float bf2f(unsigned short b) {
    union { unsigned u; float f; } v; v.u = ((unsigned)b) << 16;
    return v.f;
}
__device__ __forceinline__ float sigf(float x) {
    return 1.0f / (1.0f + __expf(-x));
}
__device__ __forceinline__ float tanh_fast(float x) {
    float t = __expf(-2.0f * fabsf(x));
    float r = (1.0f - t) / (1.0f + t);
    return copysignf(r, x);
}

// ---------------- Kernel 1: x [B,S,D] fp32 -> xb [S,B,D] bf16 ----------------
__global__ void __launch_bounds__(256) k_convert_x(const float* __restrict__ x,
                                                   unsigned short* __restrict__ xb) {
    int idx = blockIdx.x * 256 + threadIdx.x;      // over B*S*(D/8)
    int d8  = idx & 31;                            // D/8 = 32
    int bs  = idx >> 5;                            // b*SLEN + s
    int s   = bs & (SLEN - 1);
    int b   = bs >> 10;
    const float* src = x + ((size_t)bs * DIN) + d8 * 8;
    float4 v0 = *(const float4*)(src);
    float4 v1 = *(const float4*)(src + 4);
    unsigned short o[8] = {f2bf(v0.x), f2bf(v0.y), f2bf(v0.z), f2bf(v0.w),
                           f2bf(v1.x), f2bf(v1.y), f2bf(v1.z), f2bf(v1.w)};
    bf16x8 pack;
    #pragma unroll
    for (int i = 0; i < 8; ++i) pack[i] = (short)o[i];
    *(bf16x8*)(xb + ((size_t)(s * NB + b) * DIN) + d8 * 8) = pack;
}

// -- Kernel 2: build WT [2048][768] bf16 (WT[g*512+hc][k]) + zero h + flags --
__global__ void __launch_bounds__(256) k_build_wt(
    const float* __restrict__ Wgx, const float* __restrict__ Wix,
    const float* __restrict__ Wfx, const float* __restrict__ Wox,
    const float* __restrict__ Wgh, const float* __restrict__ Wih,
    const float* __restrict__ Wfh, const float* __restrict__ Woh,
    unsigned short* __restrict__ WT, unsigned short* __restrict__ h01) {
    int idx = blockIdx.x * 256 + threadIdx.x;      // 2048*768
    int col = idx / KTOT;
    int k   = idx - col * KTOT;
    int g   = col >> 9;
    int hc  = col & 511;
    const float* Wh[4] = {Wgh, Wih, Wfh, Woh};
    const float* Wx[4] = {Wgx, Wix, Wfx, Wox};
    float v = (k < HID) ? Wh[g][k * HID + hc] : Wx[g][(k - HID) * HID + hc];
    WT[idx] = f2bf(v);
    // zero h0, h1 (2*NB*HID u16) and the flag region (NBLK*FSTRIDE u32 = 8KB)
    if (idx < 2 * NB * HID + NBLK * FSTRIDE * 2) h01[idx] = 0;
}

// x-part of the gate GEMM (K = 512..768), independent of h -> overlappable
__device__ __forceinline__ void x_mfma(f32x4 xa[2][2], const unsigned short* xs,
                                       const unsigned short (*wt)[LDSK],
                                       int w, int tc0, int g4) {
    #pragma unroll
    for (int m = 0; m < 2; ++m)
        #pragma unroll
        for (int n = 0; n < 2; ++n) xa[m][n] = (f32x4){0.f, 0.f, 0.f, 0.f};
    #pragma unroll
    for (int kf = 0; kf < DIN / 32; ++kf) {        // 8 k-steps
        const unsigned short* base = xs + (size_t)(32 * w + tc0) * DIN + kf * 32 + g4 * 8;
        bf16x8 a0 = *(const bf16x8*)(base);
        bf16x8 a1 = *(const bf16x8*)(base + 16 * DIN);
        bf16x8 b0 = *(const bf16x8*)&wt[tc0][HID + kf * 32 + g4 * 8];
        bf16x8 b1 = *(const bf16x8*)&wt[16 + tc0][HID + kf * 32 + g4 * 8];
        xa[0][0] = __builtin_amdgcn_mfma_f32_16x16x32_bf16(a0, b0, xa[0][0], 0, 0, 0);
        xa[0][1] = __builtin_amdgcn_mfma_f32_16x16x32_bf16(a0, b1, xa[0][1], 0, 0, 0);
        xa[1][0] = __builtin_amdgcn_mfma_f32_16x16x32_bf16(a1, b0, xa[1][0], 0, 0, 0);
        xa[1][1] = __builtin_amdgcn_mfma_f32_16x16x32_bf16(a1, b1, xa[1][1], 0, 0, 0);
    }
}

// ---------------- Kernel 3: persistent LSTM scan, custom barrier ----------------
__global__ void __launch_bounds__(256) k_scan(
    const unsigned short* __restrict__ xb, const unsigned short* __restrict__ WT,
    unsigned short* __restrict__ h0, unsigned short* __restrict__ h1,
    unsigned int* __restrict__ flags,
    const float* __restrict__ bg, const float* __restrict__ bi,
    const float* __restrict__ bfp, const float* __restrict__ bo,
    const float* __restrict__ Wph, const float* __restrict__ bp,
    float* __restrict__ out) {
    __shared__ unsigned short wt_lds[TN][LDSK];

    const int j   = blockIdx.x;          // 0..63, owns h-cols [j*8, j*8+8)
    const int tid = threadIdx.x;
    const int w   = tid >> 6;            // wave 0..3 -> rows [32w, 32w+32)
    const int l   = tid & 63;
    const int colbase = j * CH;

    // stage this block's 32x768 weight slice into LDS (once)
    for (int it = tid; it < TN * (KTOT / 8); it += 256) {
        int r  = it / (KTOT / 8);
        int c8 = it - r * (KTOT / 8);
        int g  = r >> 3, hc = r & 7;
        bf16x8 v = *(const bf16x8*)(WT + (size_t)(g * HID + colbase + hc) * KTOT + c8 * 8);
        *(bf16x8*)&wt_lds[r][c8 * 8] = v;
    }
    __syncthreads();

    const int  tc0  = l & 15;            // tile col of nfrag0 (nfrag1 = +16)
    const int  g4   = l >> 4;            // row group within fragment
    const bool lead = (tc0 < 8);
    const float* barr[4] = {bg, bi, bfp, bo};
    const float bias0 = barr[tc0 >> 3][colbase + (tc0 & 7)];
    const float bias1 = barr[2 + (tc0 >> 3)][colbase + (tc0 & 7)];

    float c_st[2][4];
    #pragma unroll
    for (int m = 0; m < 2; ++m)
        #pragma unroll
        for (int r = 0; r < 4; ++r) c_st[m][r] = 0.0f;

    unsigned short* hb[2] = {h0, h1};

    // x-part for step 0 (h0 is zeroed, so step 0's h-part adds zeros -- still executed, harmless)
    f32x4 xacc[2][2];
    x_mfma(xacc, xb, wt_lds, w, tc0, g4);

    for (int s = 0; s < SLEN; ++s) {
        // ---- barrier wait: all blocks done with step s-1 ----
        if (tid < 64) {
            unsigned v;
            do {
                v = __hip_atomic_load(&flags[tid * FSTRIDE], __ATOMIC_RELAXED,
                                      __HIP_MEMORY_SCOPE_AGENT);
            } while (__any(v < (unsigned)s));
        }
        __syncthreads();
        __builtin_amdgcn_fence(__ATOMIC_ACQUIRE, "agent");

        const unsigned short* hprev = hb[s & 1];
        unsigned short*       hnext = hb[(s + 1) & 1];

        f32x4 acc[2][2];
        #pragma unroll
        for (int m = 0; m < 2; ++m)
            #pragma unroll
            for (int n = 0; n < 2; ++n) acc[m][n] = xacc[m][n];

        #pragma unroll
        for (int kf = 0; kf < HID / 32; ++kf) {        // 16 h k-steps
            const unsigned short* base = hprev + (size_t)(32 * w + tc0) * HID + kf * 32 + g4 * 8;
            bf16x8 a0 = *(const bf16x8*)(base);
            bf16x8 a1 = *(const bf16x8*)(base + 16 * HID);
            bf16x8 b0 = *(const bf16x8*)&wt_lds[tc0][kf * 32 + g4 * 8];
            bf16x8 b1 = *(const bf16x8*)&wt_lds[16 + tc0][kf * 32 + g4 * 8];
            acc[0][0] = __builtin_amdgcn_mfma_f32_16x16x32_bf16(a0, b0, acc[0][0], 0, 0, 0);
            acc[0][1] = __builtin_amdgcn_mfma_f32_16x16x32_bf16(a0, b1, acc[0][1], 0, 0, 0);
            acc[1][0] = __builtin_amdgcn_mfma_f32_16x16x32_bf16(a1, b0, acc[1][0], 0, 0, 0);
            acc[1][1] = __builtin_amdgcn_mfma_f32_16x16x32_bf16(a1, b1, acc[1][1], 0, 0, 0);
        }

        // elementwise gate update: lane pair (l, l^8) holds (g,f) / (i,o) for same hc
        #pragma unroll
        for (int m = 0; m < 2; ++m) {
            #pragma unroll
            for (int r = 0; r < 4; ++r) {
                float p0 = acc[m][0][r] + bias0;
                float p1 = acc[m][1][r] + bias1;
                float a0 = lead ? tanh_fast(p0) : sigf(p0);   // g : i
                float a1 = sigf(p1);                          // f : o
                float e0 = __shfl_xor(a0, 8);
                float e1 = __shfl_xor(a1, 8);
                if (lead) {
                    float gg = a0, ff = a1, ii = e0, oo = e1;
                    float c  = gg * ii + c_st[m][r] * ff;
                    c_st[m][r] = c;
                    float h  = tanh_fast(c) * oo;
                    int row  = 32 * w + 16 * m + 4 * g4 + r;
                    hnext[row * HID + colbase + tc0] = f2bf(h);
                }
            }
        }

        // ---- signal: stores drained by syncthreads, L2 written back by release ----
        __syncthreads();
        if (tid == 0) {
            __builtin_amdgcn_fence(__ATOMIC_RELEASE, "agent");
            __hip_atomic_store(&flags[j * FSTRIDE], (unsigned)(s + 1), __ATOMIC_RELAXED,
                               __HIP_MEMORY_SCOPE_AGENT);
        }

        // ---- overlap: x-part of NEXT step while other blocks arrive ----
        if (s + 1 < SLEN)
            x_mfma(xacc, xb + (size_t)(s + 1) * (NB * DIN), wt_lds, w, tc0, g4);
    }

    // wait for ALL blocks to finish step SLEN-1 before reading final h
    if (tid < 64) {
        unsigned v;
        do {
            v = __hip_atomic_load(&flags[tid * FSTRIDE], __ATOMIC_RELAXED,
                                  __HIP_MEMORY_SCOPE_AGENT);
        } while (__any(v < (unsigned)SLEN));
    }
    __syncthreads();
    __builtin_amdgcn_fence(__ATOMIC_ACQUIRE, "agent");

    // classifier head: final h is in h0 (SLEN even)
    int gtid = blockIdx.x * 256 + tid;
    if (gtid < NB * NCLS) {
        int row = gtid / NCLS, cls = gtid - row * NCLS;
        const unsigned short* hrow = h0 + row * HID;
        float accf = bp[cls];
        for (int k = 0; k < HID; ++k)
            accf += bf2f(hrow[k]) * Wph[k * NCLS + cls];
        out[gtid] = accf;
    }
}

// ---------------------------------- launch ----------------------------------
extern "C" void kernel_launch(void* const* d_in, const int* in_sizes, int n_in,
                              void* d_out, int out_size, void* d_ws, size_t ws_size,
                              hipStream_t stream) {
    const float* x   = (const float*)d_in[0];
    const float* Wgx = (const float*)d_in[1];
    const float* Wix = (const float*)d_in[2];
    const float* Wfx = (const float*)d_in[3];
    const float* Wox = (const float*)d_in[4];
    const float* Wgh = (const float*)d_in[5];
    const float* Wih = (const float*)d_in[6];
    const float* Wfh = (const float*)d_in[7];
    const float* Woh = (const float*)d_in[8];
    const float* bg  = (const float*)d_in[9];
    const float* bi  = (const float*)d_in[10];
    const float* bfp = (const float*)d_in[11];
    const float* bo  = (const float*)d_in[12];
    const float* Wph = (const float*)d_in[13];
    const float* bp  = (const float*)d_in[14];
    float* out = (float*)d_out;

    unsigned short* xb    = (unsigned short*)d_ws;               // 1024*128*256
    unsigned short* WT    = xb + (size_t)SLEN * NB * DIN;        // 2048*768
    unsigned short* h0    = WT + (size_t)4 * HID * KTOT;         // 128*512
    unsigned short* h1    = h0 + NB * HID;
    unsigned int*   flags = (unsigned int*)(h1 + NB * HID);      // 64*32 u32

    hipLaunchKernelGGL(k_convert_x, dim3(NB * SLEN * (DIN / 8) / 256), dim3(256), 0, stream, x, xb);
    hipLaunchKernelGGL(k_build_wt, dim3(4 * HID * KTOT / 256), dim3(256), 0, stream,
                       Wgx, Wix, Wfx, Wox, Wgh, Wih, Wfh, Woh, WT, h0);

    hipLaunchKernelGGL(k_scan, dim3(NBLK), dim3(256), 0, stream,
                       (const unsigned short*)xb, (const unsigned short*)WT, h0, h1, flags,
                       bg, bi, bfp, bo, Wph, bp, out);
}